// Round 1
// baseline (887.893 us; speedup 1.0000x reference)
//
#include <hip/hip_runtime.h>
#include <hip/hip_bf16.h>
#include <stdint.h>

// Problem constants (from setup_inputs): x[4096,4096] f32, qweight[4096,1376] i32,
// scales[32,11008] f32, qzeros[32,1376] i32, group_size=128. out[4096,11008] f32.
#define M_DIM 4096
#define K_DIM 4096
#define N_DIM 11008
#define OPACK (N_DIM / 8)   // 1376
#define GSZ   128

typedef __attribute__((ext_vector_type(8))) short short8;        // 8 bf16 = 4 VGPRs (MFMA A/B frag)
typedef __attribute__((ext_vector_type(4))) float floatx4;       // MFMA C/D frag
typedef __attribute__((ext_vector_type(4))) unsigned int uintx4; // 16B vector

static __device__ __forceinline__ unsigned short f32_to_bf16_rne(float f) {
    union { float f; unsigned int u; } c; c.f = f;
    unsigned int u = c.u;
    u += 0x7fffu + ((u >> 16) & 1u);   // round-to-nearest-even (no NaN inputs here)
    return (unsigned short)(u >> 16);
}

// async global->LDS, 16B per lane. LDS dest must be wave-uniform base + lane*16.
static __device__ __forceinline__ void load16_lds(const void* gptr, void* lptr) {
    __builtin_amdgcn_global_load_lds(
        (__attribute__((address_space(1))) void*)gptr,
        (__attribute__((address_space(3))) void*)lptr,
        16, 0, 0);
}

// ---------------------------------------------------------------------------
// Kernel 1: x fp32 [M][K] -> bf16 (row-major, same layout)
// ---------------------------------------------------------------------------
__global__ __launch_bounds__(256)
void convert_x_kernel(const float* __restrict__ x, unsigned short* __restrict__ xb) {
    const int idx = (blockIdx.x * 256 + threadIdx.x) * 8;
    floatx4 v0 = *(const floatx4*)(x + idx);
    floatx4 v1 = *(const floatx4*)(x + idx + 4);
    unsigned short r[8];
#pragma unroll
    for (int i = 0; i < 4; i++) {
        r[i]     = f32_to_bf16_rne(v0[i]);
        r[4 + i] = f32_to_bf16_rne(v1[i]);
    }
    *(uintx4*)(xb + idx) = *(const uintx4*)r;
}

// ---------------------------------------------------------------------------
// Kernel 2: dequant int4 -> bf16, TRANSPOSED: Wt[o][i] = (nib(qw[i][o]) - nib(qz[g][o])) * s[g][o]
// One thread: fixed o, 32 consecutive i -> one 64B contiguous store (full cachelines).
// 8 adjacent lanes (o..o+7) share each packed qweight dword (HW broadcast).
// i-range 32 always sits inside one group of 128, so g/z/s are per-thread uniform.
// ---------------------------------------------------------------------------
__global__ __launch_bounds__(256)
void dequant_kernel(const int* __restrict__ qweight, const float* __restrict__ scales,
                    const int* __restrict__ qzeros, unsigned short* __restrict__ Wt) {
    const int o  = blockIdx.x * 256 + threadIdx.x;   // [0, 11008)
    const int i0 = blockIdx.y * 32;                  // [0, 4096)
    const int g  = i0 >> 7;
    const int op = o >> 3;
    const int sh = (o & 7) * 4;
    const int z  = (qzeros[g * OPACK + op] >> sh) & 15;
    const float s = scales[g * N_DIM + o];
    unsigned short buf[32];
#pragma unroll
    for (int k = 0; k < 32; k++) {
        const int q   = qweight[(i0 + k) * OPACK + op];
        const float w = (float)(((q >> sh) & 15) - z) * s;
        buf[k] = f32_to_bf16_rne(w);
    }
    uintx4* dst = (uintx4*)(Wt + (size_t)o * K_DIM + i0);
    const uintx4* src = (const uintx4*)buf;
#pragma unroll
    for (int t = 0; t < 4; t++) dst[t] = src[t];
}

// ---------------------------------------------------------------------------
// Kernel 3: C[M][N] f32 = Xb[M][K] (bf16) @ Wt[N][K]^T (bf16)
// m97 structure: 128x128 block tile, BK=32, 4 waves, 4x4 mfma_f32_16x16x32_bf16
// per wave, global_load_lds width-16 staging, single LDS buffer, 2 barriers/iter.
// ---------------------------------------------------------------------------
__global__ __launch_bounds__(256)
void gemm_kernel(const unsigned short* __restrict__ X,   // [M][K] bf16
                 const unsigned short* __restrict__ Wt,  // [N][K] bf16
                 float* __restrict__ C) {                // [M][N] f32
    __shared__ short As[128 * 32];   // 8 KB, row-major [m][k], row stride 32 (no pad: load_lds order)
    __shared__ short Bs[128 * 32];   // 8 KB, row-major [n][k]

    const int tid  = threadIdx.x;
    const int wave = tid >> 6;
    const int lane = tid & 63;
    const int n0 = blockIdx.x * 128;
    const int m0 = blockIdx.y * 128;

    const int wm = (wave >> 1) * 64;
    const int wn = (wave & 1) * 64;

    // staging: 512 chunks of 16B per tile; thread t handles chunks t and t+256.
    // chunk c -> row c>>2, col8 (c&3)*8; LDS offset c*16 == wave*1024 + lane*16 (+4096)
    const int srow = tid >> 2;
    const int scol = (tid & 3) * 8;
    const unsigned short* Ap0 = X  + (m0 + srow) * K_DIM + scol;
    const unsigned short* Ap1 = X  + (m0 + srow + 64) * K_DIM + scol;
    const unsigned short* Bp0 = Wt + (n0 + srow) * K_DIM + scol;
    const unsigned short* Bp1 = Wt + (n0 + srow + 64) * K_DIM + scol;
    char* AsB = (char*)As;
    char* BsB = (char*)Bs;
    const int l0 = tid * 16;
    const int l1 = (tid + 256) * 16;

    floatx4 acc[4][4] = {};

    const int frow = lane & 15;          // fragment row within 16
    const int kfrag = (lane >> 4) * 8;   // fragment k offset within 32

    for (int k0 = 0; k0 < K_DIM; k0 += 32) {
        __syncthreads();   // previous iter's ds_reads done before overwrite
        load16_lds(Ap0 + k0, AsB + l0);
        load16_lds(Ap1 + k0, AsB + l1);
        load16_lds(Bp0 + k0, BsB + l0);
        load16_lds(Bp1 + k0, BsB + l1);
        __syncthreads();   // drains vmcnt (global_load_lds) before use

        short8 a[4], b[4];
#pragma unroll
        for (int t = 0; t < 4; t++) {
            a[t] = *(const short8*)(As + (wm + t * 16 + frow) * 32 + kfrag);
            b[t] = *(const short8*)(Bs + (wn + t * 16 + frow) * 32 + kfrag);
        }
#pragma unroll
        for (int i = 0; i < 4; i++)
#pragma unroll
            for (int j = 0; j < 4; j++)
                acc[i][j] = __builtin_amdgcn_mfma_f32_16x16x32_bf16(a[i], b[j], acc[i][j], 0, 0, 0);
    }

    // epilogue: C/D layout col=lane&15, row=(lane>>4)*4+reg  [verified m89/m91]
    const int crow = (lane >> 4) * 4;
    const int ccol = lane & 15;
#pragma unroll
    for (int i = 0; i < 4; i++) {
#pragma unroll
        for (int j = 0; j < 4; j++) {
            float* Cp = C + (m0 + wm + i * 16 + crow) * N_DIM + (n0 + wn + j * 16 + ccol);
#pragma unroll
            for (int r = 0; r < 4; r++)
                Cp[r * N_DIM] = acc[i][j][r];
        }
    }
}

// ---------------------------------------------------------------------------
extern "C" void kernel_launch(void* const* d_in, const int* in_sizes, int n_in,
                              void* d_out, int out_size, void* d_ws, size_t ws_size,
                              hipStream_t stream) {
    const float* x       = (const float*)d_in[0];
    const int*   qweight = (const int*)d_in[1];
    const float* scales  = (const float*)d_in[2];
    const int*   qzeros  = (const int*)d_in[3];
    // d_in[4] = group_size scalar (always 128 per setup_inputs) -- baked in.
    float* out = (float*)d_out;

    // ws layout: Xb bf16 [M][K] (33.5 MB) | Wt bf16 [N][K] (90.2 MB) -> needs ~124 MB
    unsigned short* Xb = (unsigned short*)d_ws;
    unsigned short* Wt = (unsigned short*)((char*)d_ws + (size_t)M_DIM * K_DIM * 2);

    convert_x_kernel<<<(M_DIM * K_DIM) / (256 * 8), 256, 0, stream>>>(x, Xb);
    dequant_kernel<<<dim3(N_DIM / 256, K_DIM / 32), 256, 0, stream>>>(qweight, scales, qzeros, Wt);
    gemm_kernel<<<dim3(N_DIM / 128, M_DIM / 128), 256, 0, stream>>>(Xb, Wt, out);
}

// Round 2
// 818.657 us; speedup vs baseline: 1.0846x; 1.0846x over previous
//
#include <hip/hip_runtime.h>
#include <hip/hip_bf16.h>
#include <stdint.h>

// Problem constants (from setup_inputs): x[4096,4096] f32, qweight[4096,1376] i32,
// scales[32,11008] f32, qzeros[32,1376] i32, group_size=128. out[4096,11008] f32.
#define M_DIM 4096
#define K_DIM 4096
#define N_DIM 11008
#define OPACK (N_DIM / 8)   // 1376
#define GSZ   128

#define M_TILES (M_DIM / 128)   // 32
#define N_TILES (N_DIM / 128)   // 86

typedef __attribute__((ext_vector_type(8))) short short8;        // 8 bf16 = 4 VGPRs (MFMA A/B frag)
typedef __attribute__((ext_vector_type(4))) float floatx4;       // MFMA C/D frag
typedef __attribute__((ext_vector_type(4))) unsigned int uintx4; // 16B vector

static __device__ __forceinline__ unsigned short f32_to_bf16_rne(float f) {
    union { float f; unsigned int u; } c; c.f = f;
    unsigned int u = c.u;
    u += 0x7fffu + ((u >> 16) & 1u);   // round-to-nearest-even (no NaN inputs here)
    return (unsigned short)(u >> 16);
}

// async global->LDS, 16B per lane. LDS dest must be wave-uniform base + lane*16.
static __device__ __forceinline__ void load16_lds(const void* gptr, void* lptr) {
    __builtin_amdgcn_global_load_lds(
        (__attribute__((address_space(1))) void*)gptr,
        (__attribute__((address_space(3))) void*)lptr,
        16, 0, 0);
}

// ---------------------------------------------------------------------------
// Kernel 1: x fp32 [M][K] -> bf16 (row-major, same layout)
// ---------------------------------------------------------------------------
__global__ __launch_bounds__(256)
void convert_x_kernel(const float* __restrict__ x, unsigned short* __restrict__ xb) {
    const int idx = (blockIdx.x * 256 + threadIdx.x) * 8;
    floatx4 v0 = *(const floatx4*)(x + idx);
    floatx4 v1 = *(const floatx4*)(x + idx + 4);
    unsigned short r[8];
#pragma unroll
    for (int i = 0; i < 4; i++) {
        r[i]     = f32_to_bf16_rne(v0[i]);
        r[4 + i] = f32_to_bf16_rne(v1[i]);
    }
    *(uintx4*)(xb + idx) = *(const uintx4*)r;
}

// ---------------------------------------------------------------------------
// Kernel 2: dequant int4 -> bf16, TRANSPOSED: Wt[o][i] = (nib(qw[i][o]) - nib(qz[g][o])) * s[g][o]
// One thread: fixed o, 32 consecutive i -> one 64B contiguous store (full cachelines).
// 8 adjacent lanes (o..o+7) share each packed qweight dword (HW broadcast).
// i-range 32 always sits inside one group of 128, so g/z/s are per-thread uniform.
// ---------------------------------------------------------------------------
__global__ __launch_bounds__(256)
void dequant_kernel(const int* __restrict__ qweight, const float* __restrict__ scales,
                    const int* __restrict__ qzeros, unsigned short* __restrict__ Wt) {
    const int o  = blockIdx.x * 256 + threadIdx.x;   // [0, 11008)
    const int i0 = blockIdx.y * 32;                  // [0, 4096)
    const int g  = i0 >> 7;
    const int op = o >> 3;
    const int sh = (o & 7) * 4;
    const int z  = (qzeros[g * OPACK + op] >> sh) & 15;
    const float s = scales[g * N_DIM + o];
    unsigned short buf[32];
#pragma unroll
    for (int k = 0; k < 32; k++) {
        const int q   = qweight[(i0 + k) * OPACK + op];
        const float w = (float)(((q >> sh) & 15) - z) * s;
        buf[k] = f32_to_bf16_rne(w);
    }
    uintx4* dst = (uintx4*)(Wt + (size_t)o * K_DIM + i0);
    const uintx4* src = (const uintx4*)buf;
#pragma unroll
    for (int t = 0; t < 4; t++) dst[t] = src[t];
}

// ---------------------------------------------------------------------------
// Kernel 3: C[M][N] f32 = Xb[M][K] (bf16) @ Wt[N][K]^T (bf16)
// m97 structure: 128x128 block tile, BK=32, 4 waves, 4x4 mfma_f32_16x16x32_bf16.
// 1D grid + XCD-locality swizzle:
//   xcd = pid & 7 (dispatch round-robins pid%8 across the 8 XCDs)
//   XCD x owns m-tiles [4x, 4x+4) -- its 4 MB X strip stays L2-resident;
//   within XCD, 4 blocks sharing an n-tile (Wt tile) are dispatch-adjacent,
//   so each 1 MB Wt tile is fetched to L2 once and reused 4x.
// Epilogue uses nontemporal stores: the 176 MB C stream must not evict
// X+Wt (124 MB) from L2/L3 (round-1 FETCH was 14x compulsory).
// ---------------------------------------------------------------------------
__global__ __launch_bounds__(256)
void gemm_kernel(const unsigned short* __restrict__ X,   // [M][K] bf16
                 const unsigned short* __restrict__ Wt,  // [N][K] bf16
                 float* __restrict__ C) {                // [M][N] f32
    __shared__ short As[128 * 32];   // 8 KB, row-major [m][k], row stride 32 (no pad: load_lds order)
    __shared__ short Bs[128 * 32];   // 8 KB, row-major [n][k]

    const int tid  = threadIdx.x;
    const int wave = tid >> 6;
    const int lane = tid & 63;

    // XCD-locality swizzle: pid = xcd + 8*(4*n_tile + mm), m_tile = xcd*4 + mm
    const int pid    = blockIdx.x;
    const int xcd    = pid & 7;
    const int loc    = pid >> 3;          // [0, 344)
    const int m_tile = xcd * 4 + (loc & 3);
    const int n_tile = loc >> 2;          // [0, 86)
    const int n0 = n_tile * 128;
    const int m0 = m_tile * 128;

    const int wm = (wave >> 1) * 64;
    const int wn = (wave & 1) * 64;

    // staging: 512 chunks of 16B per tile; thread t handles chunks t and t+256.
    const int srow = tid >> 2;
    const int scol = (tid & 3) * 8;
    const unsigned short* Ap0 = X  + (m0 + srow) * K_DIM + scol;
    const unsigned short* Ap1 = X  + (m0 + srow + 64) * K_DIM + scol;
    const unsigned short* Bp0 = Wt + (n0 + srow) * K_DIM + scol;
    const unsigned short* Bp1 = Wt + (n0 + srow + 64) * K_DIM + scol;
    char* AsB = (char*)As;
    char* BsB = (char*)Bs;
    const int l0 = tid * 16;
    const int l1 = (tid + 256) * 16;

    floatx4 acc[4][4] = {};

    const int frow = lane & 15;          // fragment row within 16
    const int kfrag = (lane >> 4) * 8;   // fragment k offset within 32

    for (int k0 = 0; k0 < K_DIM; k0 += 32) {
        __syncthreads();   // previous iter's ds_reads done before overwrite
        load16_lds(Ap0 + k0, AsB + l0);
        load16_lds(Ap1 + k0, AsB + l1);
        load16_lds(Bp0 + k0, BsB + l0);
        load16_lds(Bp1 + k0, BsB + l1);
        __syncthreads();   // drains vmcnt (global_load_lds) before use

        short8 a[4], b[4];
#pragma unroll
        for (int t = 0; t < 4; t++) {
            a[t] = *(const short8*)(As + (wm + t * 16 + frow) * 32 + kfrag);
            b[t] = *(const short8*)(Bs + (wn + t * 16 + frow) * 32 + kfrag);
        }
#pragma unroll
        for (int i = 0; i < 4; i++)
#pragma unroll
            for (int j = 0; j < 4; j++)
                acc[i][j] = __builtin_amdgcn_mfma_f32_16x16x32_bf16(a[i], b[j], acc[i][j], 0, 0, 0);
    }

    // epilogue: C/D layout col=lane&15, row=(lane>>4)*4+reg  [verified m89/m91]
    // nontemporal: C is write-once, never re-read -- keep it out of L2/L3.
    const int crow = (lane >> 4) * 4;
    const int ccol = lane & 15;
#pragma unroll
    for (int i = 0; i < 4; i++) {
#pragma unroll
        for (int j = 0; j < 4; j++) {
            float* Cp = C + (m0 + wm + i * 16 + crow) * N_DIM + (n0 + wn + j * 16 + ccol);
#pragma unroll
            for (int r = 0; r < 4; r++)
                __builtin_nontemporal_store(acc[i][j][r], Cp + r * N_DIM);
        }
    }
}

// ---------------------------------------------------------------------------
extern "C" void kernel_launch(void* const* d_in, const int* in_sizes, int n_in,
                              void* d_out, int out_size, void* d_ws, size_t ws_size,
                              hipStream_t stream) {
    const float* x       = (const float*)d_in[0];
    const int*   qweight = (const int*)d_in[1];
    const float* scales  = (const float*)d_in[2];
    const int*   qzeros  = (const int*)d_in[3];
    // d_in[4] = group_size scalar (always 128 per setup_inputs) -- baked in.
    float* out = (float*)d_out;

    // ws layout: Xb bf16 [M][K] (33.5 MB) | Wt bf16 [N][K] (90.2 MB) -> needs ~124 MB
    unsigned short* Xb = (unsigned short*)d_ws;
    unsigned short* Wt = (unsigned short*)((char*)d_ws + (size_t)M_DIM * K_DIM * 2);

    convert_x_kernel<<<(M_DIM * K_DIM) / (256 * 8), 256, 0, stream>>>(x, Xb);
    dequant_kernel<<<dim3(N_DIM / 256, K_DIM / 32), 256, 0, stream>>>(qweight, scales, qzeros, Wt);
    gemm_kernel<<<M_TILES * N_TILES, 256, 0, stream>>>(Xb, Wt, out);
}

// Round 3
// 696.669 us; speedup vs baseline: 1.2745x; 1.1751x over previous
//
#include <hip/hip_runtime.h>
#include <hip/hip_bf16.h>
#include <stdint.h>

// Problem constants (from setup_inputs): x[4096,4096] f32, qweight[4096,1376] i32,
// scales[32,11008] f32, qzeros[32,1376] i32, group_size=128. out[4096,11008] f32.
#define M_DIM 4096
#define K_DIM 4096
#define N_DIM 11008
#define OPACK (N_DIM / 8)   // 1376
#define GSZ   128

#define M_TILES (M_DIM / 128)   // 32
#define N_TILES (N_DIM / 128)   // 86
#define K_ITERS (K_DIM / 32)    // 128

typedef __attribute__((ext_vector_type(8))) short short8;        // 8 bf16 = 4 VGPRs (MFMA A/B frag)
typedef __attribute__((ext_vector_type(4))) float floatx4;       // MFMA C/D frag
typedef __attribute__((ext_vector_type(4))) unsigned int uintx4; // 16B vector

static __device__ __forceinline__ unsigned short f32_to_bf16_rne(float f) {
    union { float f; unsigned int u; } c; c.f = f;
    unsigned int u = c.u;
    u += 0x7fffu + ((u >> 16) & 1u);   // round-to-nearest-even (no NaN inputs here)
    return (unsigned short)(u >> 16);
}

// async global->LDS, 16B per lane. LDS dest must be wave-uniform base + lane*16.
static __device__ __forceinline__ void load16_lds(const void* gptr, void* lptr) {
    __builtin_amdgcn_global_load_lds(
        (__attribute__((address_space(1))) void*)gptr,
        (__attribute__((address_space(3))) void*)lptr,
        16, 0, 0);
}

// ---------------------------------------------------------------------------
// Kernel 1: x fp32 [M][K] -> bf16 (row-major, same layout)
// ---------------------------------------------------------------------------
__global__ __launch_bounds__(256)
void convert_x_kernel(const float* __restrict__ x, unsigned short* __restrict__ xb) {
    const int idx = (blockIdx.x * 256 + threadIdx.x) * 8;
    floatx4 v0 = *(const floatx4*)(x + idx);
    floatx4 v1 = *(const floatx4*)(x + idx + 4);
    unsigned short r[8];
#pragma unroll
    for (int i = 0; i < 4; i++) {
        r[i]     = f32_to_bf16_rne(v0[i]);
        r[4 + i] = f32_to_bf16_rne(v1[i]);
    }
    *(uintx4*)(xb + idx) = *(const uintx4*)r;
}

// ---------------------------------------------------------------------------
// Kernel 2: dequant int4 -> bf16, TRANSPOSED: Wt[o][i] = (nib(qw[i][o]) - nib(qz[g][o])) * s[g][o]
// One thread: fixed o, 32 consecutive i -> one 64B contiguous store (full cachelines).
// 8 adjacent lanes (o..o+7) share each packed qweight dword (HW broadcast).
// ---------------------------------------------------------------------------
__global__ __launch_bounds__(256)
void dequant_kernel(const int* __restrict__ qweight, const float* __restrict__ scales,
                    const int* __restrict__ qzeros, unsigned short* __restrict__ Wt) {
    const int o  = blockIdx.x * 256 + threadIdx.x;   // [0, 11008)
    const int i0 = blockIdx.y * 32;                  // [0, 4096)
    const int g  = i0 >> 7;
    const int op = o >> 3;
    const int sh = (o & 7) * 4;
    const int z  = (qzeros[g * OPACK + op] >> sh) & 15;
    const float s = scales[g * N_DIM + o];
    unsigned short buf[32];
#pragma unroll
    for (int k = 0; k < 32; k++) {
        const int q   = qweight[(i0 + k) * OPACK + op];
        const float w = (float)(((q >> sh) & 15) - z) * s;
        buf[k] = f32_to_bf16_rne(w);
    }
    uintx4* dst = (uintx4*)(Wt + (size_t)o * K_DIM + i0);
    const uintx4* src = (const uintx4*)buf;
#pragma unroll
    for (int t = 0; t < 4; t++) dst[t] = src[t];
}

// ---------------------------------------------------------------------------
// Kernel 3: C[M][N] f32 = Xb[M][K] (bf16) @ Wt[N][K]^T (bf16)
// 128x128 block tile, BK=32, 4 waves, 4x4 mfma_f32_16x16x32_bf16.
// ROUND 3: single-barrier double-buffered K-loop. Per iteration:
//   issue global_load_lds -> buf[next]; compute from buf[cur] (lgkm only);
//   __syncthreads() (compiler's vmcnt(0) drain lands AFTER compute).
// Next-tile L3 loads (~500cyc) overlap the compute phase instead of stalling
// before it (round-2: 43% both-pipes-idle from exposed drain at 2 barriers/iter).
// LDS 32 KB/block -> 5 blocks/CU, same as the 88-VGPR cap.
// XCD-locality swizzle: xcd = pid&7 owns m-tiles [4*xcd, 4*xcd+4); 4 blocks
// sharing a Wt tile are dispatch-adjacent on one XCD (L2 reuse 4x).
// ---------------------------------------------------------------------------
__global__ __launch_bounds__(256)
void gemm_kernel(const unsigned short* __restrict__ X,   // [M][K] bf16
                 const unsigned short* __restrict__ Wt,  // [N][K] bf16
                 float* __restrict__ C) {                // [M][N] f32
    __shared__ short As[2][128 * 32];   // 2 x 8 KB
    __shared__ short Bs[2][128 * 32];   // 2 x 8 KB

    const int tid  = threadIdx.x;
    const int wave = tid >> 6;
    const int lane = tid & 63;

    // XCD-locality swizzle: pid = xcd + 8*(4*n_tile + mm), m_tile = xcd*4 + mm
    const int pid    = blockIdx.x;
    const int xcd    = pid & 7;
    const int loc    = pid >> 3;          // [0, 344)
    const int m_tile = xcd * 4 + (loc & 3);
    const int n_tile = loc >> 2;          // [0, 86)
    const int n0 = n_tile * 128;
    const int m0 = m_tile * 128;

    const int wm = (wave >> 1) * 64;
    const int wn = (wave & 1) * 64;

    // staging: 512 chunks of 16B per tile; thread t handles chunks t and t+256.
    const int srow = tid >> 2;
    const int scol = (tid & 3) * 8;
    const unsigned short* Ap0 = X  + (m0 + srow) * K_DIM + scol;
    const unsigned short* Ap1 = X  + (m0 + srow + 64) * K_DIM + scol;
    const unsigned short* Bp0 = Wt + (n0 + srow) * K_DIM + scol;
    const unsigned short* Bp1 = Wt + (n0 + srow + 64) * K_DIM + scol;
    const int l0 = tid * 16;
    const int l1 = (tid + 256) * 16;

    floatx4 acc[4][4] = {};

    const int frow  = lane & 15;         // fragment row within 16
    const int kfrag = (lane >> 4) * 8;   // fragment k offset within 32

    // prologue: stage tile 0 into buffer 0
    load16_lds(Ap0, (char*)As[0] + l0);
    load16_lds(Ap1, (char*)As[0] + l1);
    load16_lds(Bp0, (char*)Bs[0] + l0);
    load16_lds(Bp1, (char*)Bs[0] + l1);
    __syncthreads();

    for (int it = 0; it < K_ITERS; ++it) {
        const int cur = it & 1;
        const int nxt = cur ^ 1;
        if (it + 1 < K_ITERS) {
            const int kn = (it + 1) * 32;
            load16_lds(Ap0 + kn, (char*)As[nxt] + l0);
            load16_lds(Ap1 + kn, (char*)As[nxt] + l1);
            load16_lds(Bp0 + kn, (char*)Bs[nxt] + l0);
            load16_lds(Bp1 + kn, (char*)Bs[nxt] + l1);
        }

        const short* Ac = As[cur];
        const short* Bc = Bs[cur];
        short8 a[4], b[4];
#pragma unroll
        for (int t = 0; t < 4; t++) {
            a[t] = *(const short8*)(Ac + (wm + t * 16 + frow) * 32 + kfrag);
            b[t] = *(const short8*)(Bc + (wn + t * 16 + frow) * 32 + kfrag);
        }
#pragma unroll
        for (int i = 0; i < 4; i++)
#pragma unroll
            for (int j = 0; j < 4; j++)
                acc[i][j] = __builtin_amdgcn_mfma_f32_16x16x32_bf16(a[i], b[j], acc[i][j], 0, 0, 0);

        // one barrier per iter: drains vmcnt (next tile staged) + lgkmcnt
        // (all waves done reading buf[cur], safe to overwrite next iter)
        __syncthreads();
    }

    // epilogue: C/D layout col=lane&15, row=(lane>>4)*4+reg  [verified m89/m91]
    // nontemporal: C is write-once, never re-read -- keep it out of L2/L3.
    const int crow = (lane >> 4) * 4;
    const int ccol = lane & 15;
#pragma unroll
    for (int i = 0; i < 4; i++) {
#pragma unroll
        for (int j = 0; j < 4; j++) {
            float* Cp = C + (m0 + wm + i * 16 + crow) * N_DIM + (n0 + wn + j * 16 + ccol);
#pragma unroll
            for (int r = 0; r < 4; r++)
                __builtin_nontemporal_store(acc[i][j][r], Cp + r * N_DIM);
        }
    }
}

// ---------------------------------------------------------------------------
extern "C" void kernel_launch(void* const* d_in, const int* in_sizes, int n_in,
                              void* d_out, int out_size, void* d_ws, size_t ws_size,
                              hipStream_t stream) {
    const float* x       = (const float*)d_in[0];
    const int*   qweight = (const int*)d_in[1];
    const float* scales  = (const float*)d_in[2];
    const int*   qzeros  = (const int*)d_in[3];
    // d_in[4] = group_size scalar (always 128 per setup_inputs) -- baked in.
    float* out = (float*)d_out;

    // ws layout: Xb bf16 [M][K] (33.5 MB) | Wt bf16 [N][K] (90.2 MB) -> needs ~124 MB
    unsigned short* Xb = (unsigned short*)d_ws;
    unsigned short* Wt = (unsigned short*)((char*)d_ws + (size_t)M_DIM * K_DIM * 2);

    convert_x_kernel<<<(M_DIM * K_DIM) / (256 * 8), 256, 0, stream>>>(x, Xb);
    dequant_kernel<<<dim3(N_DIM / 256, K_DIM / 32), 256, 0, stream>>>(qweight, scales, qzeros, Wt);
    gemm_kernel<<<M_TILES * N_TILES, 256, 0, stream>>>(Xb, Wt, out);
}